// Round 2
// 421.747 us; speedup vs baseline: 1.0411x; 1.0411x over previous
//
#include <hip/hip_runtime.h>
#include <cmath>

#define NN 8192

typedef float floatx4 __attribute__((ext_vector_type(4)));
typedef unsigned int uint;
typedef unsigned long long u64;

// ---------------------------------------------------------------------------
// h_kernel<L2>: H[ch] = X @ w_ch, output fp8 e4m3 in MFMA B-fragment order:
//   Hfrag[ch][t][tile][lane] (u64 = 8 k-elems), t=j>>5,
//   lane=(n&15)|(((j&31)>>3)<<4), tile=n>>4.
// L2=0: X = V (f32 [8192,32]).  L2=1: X = relu(sum_{c<8} Zpart[c] + gbias).
// Grid dim3(128,3): blockIdx.y = channel, block owns 64 rows of X.
// fp8 16x16x32 has the same logical A/B fragment mapping as the f16 shape
// (8 k-elems/lane), just byte-packed -> layout identical to the verified f16
// version, element size halved.
// ---------------------------------------------------------------------------
template <int L2>
__global__ __launch_bounds__(256) void h_kernel(
    const float* __restrict__ X, const float* __restrict__ w1,
    const float* __restrict__ w2, const float* __restrict__ w3,
    const float* __restrict__ gbias, u64* __restrict__ Hfrag) {
  __shared__ float wl[32][32];   // wl[d][n]
  __shared__ float Xs[64][32];
  const int tid = threadIdx.x;
  const int ch = blockIdx.y;
  const float* wsrc = (ch == 0) ? w1 : (ch == 1) ? w2 : w3;
  for (int i = tid; i < 1024; i += 256) ((float*)wl)[i] = wsrc[i];
  const size_t base = (size_t)blockIdx.x * 2048 + tid * 8;
  if (L2 == 0) {
    float4 x0 = ((const float4*)(X + base))[0];
    float4 x1 = ((const float4*)(X + base))[1];
    *((float4*)(&Xs[0][0] + tid * 8)) = x0;
    *((float4*)(&Xs[0][0] + tid * 8 + 4)) = x1;
  } else {
    float4 s0 = {0.f, 0.f, 0.f, 0.f}, s1 = {0.f, 0.f, 0.f, 0.f};
#pragma unroll
    for (int c = 0; c < 8; ++c) {
      const float4* p = (const float4*)(X + (size_t)c * NN * 32 + base);
      float4 a = p[0], b = p[1];
      s0.x += a.x; s0.y += a.y; s0.z += a.z; s0.w += a.w;
      s1.x += b.x; s1.y += b.y; s1.z += b.z; s1.w += b.w;
    }
    const int c0 = (tid * 8) & 31;
    const float4 b0 = *(const float4*)(gbias + c0);
    const float4 b1 = *(const float4*)(gbias + c0 + 4);
    s0.x += b0.x; s0.y += b0.y; s0.z += b0.z; s0.w += b0.w;
    s1.x += b1.x; s1.y += b1.y; s1.z += b1.z; s1.w += b1.w;
    s0.x = s0.x > 0.f ? s0.x : 0.f; s0.y = s0.y > 0.f ? s0.y : 0.f;
    s0.z = s0.z > 0.f ? s0.z : 0.f; s0.w = s0.w > 0.f ? s0.w : 0.f;
    s1.x = s1.x > 0.f ? s1.x : 0.f; s1.y = s1.y > 0.f ? s1.y : 0.f;
    s1.z = s1.z > 0.f ? s1.z : 0.f; s1.w = s1.w > 0.f ? s1.w : 0.f;
    *((float4*)(&Xs[0][0] + tid * 8)) = s0;
    *((float4*)(&Xs[0][0] + tid * 8 + 4)) = s1;
  }
  __syncthreads();
  const int n = tid & 31, jb = tid >> 5;
  const int j0 = blockIdx.x * 64 + jb * 8;
  const int t = j0 >> 5;
  const int lane = (n & 15) | (((j0 & 31) >> 3) << 4);
  const int tile = n >> 4;
  float av[8];
#pragma unroll
  for (int jj = 0; jj < 8; ++jj) {
    const float4* xr = (const float4*)(&Xs[jb * 8 + jj][0]);
    float acc = 0.f;
#pragma unroll
    for (int d4 = 0; d4 < 8; ++d4) {
      float4 x = xr[d4];
      acc += x.x * wl[d4 * 4 + 0][n];
      acc += x.y * wl[d4 * 4 + 1][n];
      acc += x.z * wl[d4 * 4 + 2][n];
      acc += x.w * wl[d4 * 4 + 3][n];
    }
    av[jj] = acc;
  }
  int lo = __builtin_amdgcn_cvt_pk_fp8_f32(av[0], av[1], 0, false);
  lo = __builtin_amdgcn_cvt_pk_fp8_f32(av[2], av[3], lo, true);
  int hi = __builtin_amdgcn_cvt_pk_fp8_f32(av[4], av[5], 0, false);
  hi = __builtin_amdgcn_cvt_pk_fp8_f32(av[6], av[7], hi, true);
  size_t idx = (((size_t)ch * 256 + t) * 2 + tile) * 64 + lane;
  Hfrag[idx] = ((u64)(uint)hi << 32) | (uint)(uint)lo;
}

// ---------------------------------------------------------------------------
// SWAR one-hot build: pk holds 16 2-bit codes (low 16 bits = rowgrp0,
// high 16 = rowgrp1). For channel k: z bit 2i == (code_i == k).
// Spread 4 indicator bits (0,2,4,6 of g) to 4 fp8 bytes of value 2.0 (0x40):
// ((g*0x41041)&0x01010101)<<6.  Carry-safe on kept bits (collisions at
// 6/12/18 carry to 7/13/19, never to 0/8/16/24).  Masks are EXACT in fp8;
// epilogue scales accumulators by 0.5f to compensate the 2.0.
// ---------------------------------------------------------------------------
#define BUILD_MASK(z, r0out, r1out)                                       \
  {                                                                       \
    const uint d0 = ((((z) & 0x55u) * 0x41041u) & 0x01010101u) << 6;      \
    const uint d1 = (((((z) >> 8) & 0x55u) * 0x41041u) & 0x01010101u)     \
                    << 6;                                                 \
    const uint d2 = (((((z) >> 16) & 0x55u) * 0x41041u) & 0x01010101u)    \
                    << 6;                                                 \
    const uint d3 = (((((z) >> 24) & 0x55u) * 0x41041u) & 0x01010101u)    \
                    << 6;                                                 \
    r0out = (long long)(((u64)d1 << 32) | d0);                            \
    r1out = (long long)(((u64)d3 << 32) | d2);                            \
  }

#define MF8(A, B, C) __builtin_amdgcn_mfma_f32_16x16x32_fp8_fp8((A), (B), (C), 0, 0, 0)

// ---------------------------------------------------------------------------
// phaseB_core: software-pipelined fp8 MFMA loop. mk[8] (consume-order mask
// words) already in registers. Per k-tile: prefetch NEXT tile's 6 Hf
// B-fragments (dwordx2), SWAR-build 6 fp8 one-hot A-fragments, 12 MFMA,
// rotate. ~75 VGPRs -> callers use __launch_bounds__(256,4) with headroom.
// Epilogue: 4-wave LDS reduce, 0.5x rescale (mask value 2.0), raw partials
// -> Zpart[c][row][32]  (C/D layout: col=lane&15, row=(lane>>4)*4+reg).
// ---------------------------------------------------------------------------
__device__ __forceinline__ void phaseB_core(const uint* mk,
                                            const u64* __restrict__ Hf,
                                            float* red_raw,
                                            float* __restrict__ Zpart, int rg,
                                            int c, int tid) {
  const int w = tid >> 6, lane = tid & 63;
  const int m = lane & 15, q = lane >> 4;
  const u64* hp = Hf + (size_t)(c * 32 + w * 8) * 128 + lane;
  // prologue: tile 0 fragments
  long long b00 = hp[0],     b01 = hp[64];
  long long b10 = hp[32768], b11 = hp[32768 + 64];
  long long b20 = hp[65536], b21 = hp[65536 + 64];
  floatx4 acc00 = {0.f, 0.f, 0.f, 0.f}, acc01 = {0.f, 0.f, 0.f, 0.f};
  floatx4 acc10 = {0.f, 0.f, 0.f, 0.f}, acc11 = {0.f, 0.f, 0.f, 0.f};
#pragma unroll
  for (int tl = 0; tl < 8; ++tl) {
    long long n00, n01, n10, n11, n20, n21;
    if (tl < 7) {  // prefetch next tile while we chew on this one
      const u64* np = hp + (tl + 1) * 128;
      n00 = np[0];     n01 = np[64];
      n10 = np[32768]; n11 = np[32768 + 64];
      n20 = np[65536]; n21 = np[65536 + 64];
    }
    const uint pk = mk[tl];
    const uint x1 = pk ^ 0x55555555u;
    const uint z1 = ~(x1 | (x1 >> 1)) & 0x55555555u;
    const uint x2 = pk ^ 0xAAAAAAAAu;
    const uint z2 = ~(x2 | (x2 >> 1)) & 0x55555555u;
    const uint x3 = ~pk;
    const uint z3 = ~(x3 | (x3 >> 1)) & 0x55555555u;
    long long a1r0, a1r1, a2r0, a2r1, a3r0, a3r1;
    BUILD_MASK(z1, a1r0, a1r1);
    BUILD_MASK(z2, a2r0, a2r1);
    BUILD_MASK(z3, a3r0, a3r1);
    acc00 = MF8(a1r0, b00, acc00);
    acc00 = MF8(a2r0, b10, acc00);
    acc00 = MF8(a3r0, b20, acc00);
    acc01 = MF8(a1r0, b01, acc01);
    acc01 = MF8(a2r0, b11, acc01);
    acc01 = MF8(a3r0, b21, acc01);
    acc10 = MF8(a1r1, b00, acc10);
    acc10 = MF8(a2r1, b10, acc10);
    acc10 = MF8(a3r1, b20, acc10);
    acc11 = MF8(a1r1, b01, acc11);
    acc11 = MF8(a2r1, b11, acc11);
    acc11 = MF8(a3r1, b21, acc11);
    if (tl < 7) {
      b00 = n00; b01 = n01; b10 = n10; b11 = n11; b20 = n20; b21 = n21;
    }
  }
  // combine the 4 waves' j-slices through LDS
  float (*red)[4][64][4] = (float (*)[4][64][4])red_raw;
#pragma unroll
  for (int r = 0; r < 4; ++r) {
    red[w][0][lane][r] = acc00[r];
    red[w][1][lane][r] = acc01[r];
    red[w][2][lane][r] = acc10[r];
    red[w][3][lane][r] = acc11[r];
  }
  __syncthreads();
  if (w == 0) {
    const int rbase = rg * 32;
#pragma unroll
    for (int r = 0; r < 4; ++r) {
      const float c00 = 0.5f * (red[0][0][lane][r] + red[1][0][lane][r] +
                                red[2][0][lane][r] + red[3][0][lane][r]);
      const float c01 = 0.5f * (red[0][1][lane][r] + red[1][1][lane][r] +
                                red[2][1][lane][r] + red[3][1][lane][r]);
      const float c10 = 0.5f * (red[0][2][lane][r] + red[1][2][lane][r] +
                                red[2][2][lane][r] + red[3][2][lane][r]);
      const float c11 = 0.5f * (red[0][3][lane][r] + red[1][3][lane][r] +
                                red[2][3][lane][r] + red[3][3][lane][r]);
      const int ro0 = rbase + q * 4 + r;
      float* zp0 = Zpart + ((size_t)c * NN + ro0) * 32;
      zp0[m] = c00;
      zp0[16 + m] = c01;
      float* zp1 = Zpart + ((size_t)c * NN + ro0 + 16) * 32;
      zp1[m] = c10;
      zp1[16 + m] = c11;
    }
  }
}

// ---------------------------------------------------------------------------
// agg1_kernel (layer 1, fused pack): block (rg,c) reads adj rows rg*32..+32,
// j c*1024..+1024 with contiguous dwordx4 loads (8 rows in flight/thread),
// packs 2-bit codes into the 8KB LDS consume-order tile, dumps the tile to
// packed_g as one contiguous 8KB run for layer 2, then runs pipelined
// phase B. Grid 2048; (256,4) -> 4 blocks/CU.
// ---------------------------------------------------------------------------
__global__ __launch_bounds__(256, 4) void agg1_kernel(
    const int* __restrict__ adj, uint* __restrict__ packed_g,
    const u64* __restrict__ Hf, float* __restrict__ Zpart) {
  __shared__ char smraw[16384];
  uint* ptile = (uint*)smraw;
  const int tid = threadIdx.x;
  const int rg = blockIdx.x >> 3, c = blockIdx.x & 7;
  const int tg = tid >> 5;            // j-tile-group of 4 tiles
  const int qt = (tid >> 1) & 3;      // quad within tile
  const int t4 = (tid >> 3) & 3;      // tile within group
  const int ih = tid & 1;             // 4-j half of the 8-j quad
  const int byte_base = tg * 1024 + qt * 256 + t4 * 4 + ih;
  unsigned char* pb = (unsigned char*)ptile;
  const size_t gofs = (size_t)rg * 32 * NN + c * 1024 + tid * 4;
#pragma unroll
  for (int r0 = 0; r0 < 32; r0 += 8) {
    int4 a[8];
#pragma unroll
    for (int rr = 0; rr < 8; ++rr)
      a[rr] = *(const int4*)(adj + gofs + (size_t)(r0 + rr) * NN);
#pragma unroll
    for (int rr = 0; rr < 8; ++rr) {
      const int r = r0 + rr;
      const uint b = (uint)(a[rr].x & 3) | ((uint)(a[rr].y & 3) << 2) |
                     ((uint)(a[rr].z & 3) << 4) | ((uint)(a[rr].w & 3) << 6);
      pb[byte_base + (r & 15) * 16 + (r >> 4) * 2] = (unsigned char)b;
    }
  }
  __syncthreads();
  // contiguous 8KB packed write for layer 2
  uint* pg = packed_g + (size_t)blockIdx.x * 2048;
  *(uint4*)(pg + tid * 8) = *(const uint4*)(ptile + tid * 8);
  *(uint4*)(pg + tid * 8 + 4) = *(const uint4*)(ptile + tid * 8 + 4);
  // mask words into registers, then free ptile for the reduce buffer
  const int w = tid >> 6, lane = tid & 63;
  uint mk[8];
  *(uint4*)(mk) = *(const uint4*)(ptile + (w * 2) * 256 + lane * 4);
  *(uint4*)(mk + 4) = *(const uint4*)(ptile + (w * 2 + 1) * 256 + lane * 4);
  __syncthreads();
  phaseB_core(mk, Hf, (float*)smraw, Zpart, rg, c, tid);
}

// ---------------------------------------------------------------------------
// agg2_kernel (layer 2): mask words straight from the packed buffer
// (consume-order => 16B/lane coalesced dwordx4, L2/L3-resident), then
// pipelined phase B.
// ---------------------------------------------------------------------------
__global__ __launch_bounds__(256, 4) void agg2_kernel(
    const uint* __restrict__ packed_g, const u64* __restrict__ Hf,
    float* __restrict__ Zpart) {
  __shared__ float red_lds[4][4][64][4];
  const int tid = threadIdx.x;
  const int rg = blockIdx.x >> 3, c = blockIdx.x & 7;
  const int w = tid >> 6, lane = tid & 63;
  const uint* pg =
      packed_g + (size_t)blockIdx.x * 2048 + (w * 2) * 256 + lane * 4;
  uint mk[8];
  *(uint4*)(mk) = *(const uint4*)(pg);
  *(uint4*)(mk + 4) = *(const uint4*)(pg + 256);
  phaseB_core(mk, Hf, (float*)red_lds, Zpart, rg, c, tid);
}

// ---------------------------------------------------------------------------
// pool_kernel: partials = per-block column sums of relu(sum_{c<8} Zpart + b)
// Grid 32 x 256: block owns 256 rows.
// ---------------------------------------------------------------------------
__global__ __launch_bounds__(256) void pool_kernel(
    const float* __restrict__ Zpart, const float* __restrict__ bias,
    float* __restrict__ partials) {
  const int tid = threadIdx.x;
  const int col = tid & 31, ro = tid >> 5;
  const float b = bias[col];
  float s = 0.f;
  for (int rr = 0; rr < 32; ++rr) {
    const size_t r = (size_t)blockIdx.x * 256 + ro * 32 + rr;
    float v = b;
#pragma unroll
    for (int c = 0; c < 8; ++c) v += Zpart[(size_t)c * NN * 32 + r * 32 + col];
    s += v > 0.f ? v : 0.f;
  }
  __shared__ float red[8][32];
  red[ro][col] = s;
  __syncthreads();
  if (tid < 32) {
    float t = 0.f;
#pragma unroll
    for (int i = 0; i < 8; ++i) t += red[i][tid];
    partials[(size_t)blockIdx.x * 32 + tid] = t;
  }
}

// ---------------------------------------------------------------------------
// fc_kernel: reduce pooled partials (np x 32), fc0+relu, fc1, sigmoid
// ---------------------------------------------------------------------------
__global__ __launch_bounds__(256) void fc_kernel(
    const float* __restrict__ partials, int np, const float* __restrict__ W0,
    const float* __restrict__ b0, const float* __restrict__ W1,
    const float* __restrict__ b1, float* __restrict__ out) {
  __shared__ float acc8[8][32];
  __shared__ float z[32], y[32];
  const int tid = threadIdx.x;
  const int col = tid & 31, ch = tid >> 5;
  float s = 0.f;
  for (int i = ch; i < np; i += 8) s += partials[(size_t)i * 32 + col];
  acc8[ch][col] = s;
  __syncthreads();
  if (tid < 32) {
    float t = 0.f;
#pragma unroll
    for (int i = 0; i < 8; ++i) t += acc8[i][tid];
    z[tid] = t;
  }
  __syncthreads();
  if (tid < 32) {
    float acc = b0[tid];
    for (int n = 0; n < 32; ++n) acc += W0[tid * 32 + n] * z[n];
    y[tid] = acc > 0.f ? acc : 0.f;
  }
  __syncthreads();
  if (tid == 0) {
    float acc = b1[0];
    for (int mm = 0; mm < 32; ++mm) acc += W1[mm] * y[mm];
    out[0] = 1.f / (1.f + expf(-acc));
  }
}

extern "C" void kernel_launch(void* const* d_in, const int* in_sizes, int n_in,
                              void* d_out, int out_size, void* d_ws,
                              size_t ws_size, hipStream_t stream) {
  const float* V   = (const float*)d_in[0];
  const int*   adj = (const int*)d_in[1];
  const float *w10 = (const float*)d_in[2], *w20 = (const float*)d_in[3],
              *w30 = (const float*)d_in[4], *gb0 = (const float*)d_in[5];
  const float *w11 = (const float*)d_in[6], *w21 = (const float*)d_in[7],
              *w31 = (const float*)d_in[8], *gb1 = (const float*)d_in[9];
  const float *fW0 = (const float*)d_in[10], *fb0 = (const float*)d_in[11],
              *fW1 = (const float*)d_in[12], *fb1 = (const float*)d_in[13];
  float* out = (float*)d_out;
  char* ws = (char*)d_ws;

  u64*   Hfrag    = (u64*)ws;                   //   786,432 B (fp8 fragments)
  float* Zpart    = (float*)(ws + 786432);      // 8,388,608 B
  float* partials = (float*)(ws + 9175040);     //   262,144 B
  uint*  packed   = (uint*)(ws + 9437184);      // 16,777,216 B

  h_kernel<0><<<dim3(128, 3), 256, 0, stream>>>(V, w10, w20, w30, nullptr,
                                                Hfrag);
  agg1_kernel<<<2048, 256, 0, stream>>>(adj, packed, Hfrag, Zpart);
  h_kernel<1><<<dim3(128, 3), 256, 0, stream>>>(Zpart, w11, w21, w31, gb0,
                                                Hfrag);
  agg2_kernel<<<2048, 256, 0, stream>>>(packed, Hfrag, Zpart);
  pool_kernel<<<32, 256, 0, stream>>>(Zpart, gb1, partials);
  fc_kernel<<<1, 256, 0, stream>>>(partials, 32, fW0, fb0, fW1, fb1, out);
}

// Round 3
// 410.873 us; speedup vs baseline: 1.0686x; 1.0265x over previous
//
#include <hip/hip_runtime.h>
#include <cmath>

#define NN 8192

typedef float floatx4 __attribute__((ext_vector_type(4)));
typedef unsigned int uint;
typedef unsigned long long u64;

// ---------------------------------------------------------------------------
// h_kernel: H1[ch] = V @ w_ch, output fp8 e4m3 in MFMA B-fragment order:
//   Hfrag[ch][t][tile][lane] (u64 = 8 k-elems), t=j>>5,
//   lane=(n&15)|(((j&31)>>3)<<4), tile=n>>4.
// Grid dim3(128,3): blockIdx.y = channel, block owns 64 rows of V.
// ---------------------------------------------------------------------------
__global__ __launch_bounds__(256) void h_kernel(
    const float* __restrict__ X, const float* __restrict__ w1,
    const float* __restrict__ w2, const float* __restrict__ w3,
    u64* __restrict__ Hfrag) {
  __shared__ float wl[32][32];   // wl[d][n]
  __shared__ float Xs[64][32];
  const int tid = threadIdx.x;
  const int ch = blockIdx.y;
  const float* wsrc = (ch == 0) ? w1 : (ch == 1) ? w2 : w3;
  for (int i = tid; i < 1024; i += 256) ((float*)wl)[i] = wsrc[i];
  const size_t base = (size_t)blockIdx.x * 2048 + tid * 8;
  float4 x0 = ((const float4*)(X + base))[0];
  float4 x1 = ((const float4*)(X + base))[1];
  *((float4*)(&Xs[0][0] + tid * 8)) = x0;
  *((float4*)(&Xs[0][0] + tid * 8 + 4)) = x1;
  __syncthreads();
  const int n = tid & 31, jb = tid >> 5;
  const int j0 = blockIdx.x * 64 + jb * 8;
  const int t = j0 >> 5;
  const int lane = (n & 15) | (((j0 & 31) >> 3) << 4);
  const int tile = n >> 4;
  float av[8];
#pragma unroll
  for (int jj = 0; jj < 8; ++jj) {
    const float4* xr = (const float4*)(&Xs[jb * 8 + jj][0]);
    float acc = 0.f;
#pragma unroll
    for (int d4 = 0; d4 < 8; ++d4) {
      float4 x = xr[d4];
      acc += x.x * wl[d4 * 4 + 0][n];
      acc += x.y * wl[d4 * 4 + 1][n];
      acc += x.z * wl[d4 * 4 + 2][n];
      acc += x.w * wl[d4 * 4 + 3][n];
    }
    av[jj] = acc;
  }
  int lo = __builtin_amdgcn_cvt_pk_fp8_f32(av[0], av[1], 0, false);
  lo = __builtin_amdgcn_cvt_pk_fp8_f32(av[2], av[3], lo, true);
  int hi = __builtin_amdgcn_cvt_pk_fp8_f32(av[4], av[5], 0, false);
  hi = __builtin_amdgcn_cvt_pk_fp8_f32(av[6], av[7], hi, true);
  size_t idx = (((size_t)ch * 256 + t) * 2 + tile) * 64 + lane;
  Hfrag[idx] = ((u64)(uint)hi << 32) | (uint)(uint)lo;
}

// ---------------------------------------------------------------------------
// SWAR one-hot build: z bit 2i == (code_i == k); spread 4 indicator bits to
// 4 fp8 bytes of value 2.0 (0x40): ((g*0x41041)&0x01010101)<<6. Carry-safe
// on kept bits. Masks EXACT in fp8; epilogues rescale by 0.5f.
// ---------------------------------------------------------------------------
#define BUILD_MASK(z, r0out, r1out)                                       \
  {                                                                       \
    const uint d0 = ((((z) & 0x55u) * 0x41041u) & 0x01010101u) << 6;      \
    const uint d1 = (((((z) >> 8) & 0x55u) * 0x41041u) & 0x01010101u)     \
                    << 6;                                                 \
    const uint d2 = (((((z) >> 16) & 0x55u) * 0x41041u) & 0x01010101u)    \
                    << 6;                                                 \
    const uint d3 = (((((z) >> 24) & 0x55u) * 0x41041u) & 0x01010101u)    \
                    << 6;                                                 \
    r0out = (long long)(((u64)d1 << 32) | d0);                            \
    r1out = (long long)(((u64)d3 << 32) | d2);                            \
  }

#define MF8(A, B, C) __builtin_amdgcn_mfma_f32_16x16x32_fp8_fp8((A), (B), (C), 0, 0, 0)

// ---------------------------------------------------------------------------
// phaseB4: 4 consecutive j-tiles (one uint4 of consume-order mask words)
// against Hf fragments at hp (tl stride 128 u64; tile +64; ch +32768).
// Software-pipelined: prefetch next tile's 6 B-frags during current MFMAs.
// Accumulates into caller's 4 accs (rowgrp0/1 x colhalf0/1).
// ---------------------------------------------------------------------------
__device__ __forceinline__ void phaseB4(uint4 mkv, const u64* __restrict__ hp,
                                        floatx4& acc00, floatx4& acc01,
                                        floatx4& acc10, floatx4& acc11) {
  uint mk[4] = {mkv.x, mkv.y, mkv.z, mkv.w};
  long long b00 = (long long)hp[0],     b01 = (long long)hp[64];
  long long b10 = (long long)hp[32768], b11 = (long long)hp[32768 + 64];
  long long b20 = (long long)hp[65536], b21 = (long long)hp[65536 + 64];
#pragma unroll
  for (int tl = 0; tl < 4; ++tl) {
    long long n00, n01, n10, n11, n20, n21;
    if (tl < 3) {
      const u64* np = hp + (tl + 1) * 128;
      n00 = (long long)np[0];     n01 = (long long)np[64];
      n10 = (long long)np[32768]; n11 = (long long)np[32768 + 64];
      n20 = (long long)np[65536]; n21 = (long long)np[65536 + 64];
    }
    const uint pk = mk[tl];
    const uint x1 = pk ^ 0x55555555u;
    const uint z1 = ~(x1 | (x1 >> 1)) & 0x55555555u;
    const uint x2 = pk ^ 0xAAAAAAAAu;
    const uint z2 = ~(x2 | (x2 >> 1)) & 0x55555555u;
    const uint x3 = ~pk;
    const uint z3 = ~(x3 | (x3 >> 1)) & 0x55555555u;
    long long a1r0, a1r1, a2r0, a2r1, a3r0, a3r1;
    BUILD_MASK(z1, a1r0, a1r1);
    BUILD_MASK(z2, a2r0, a2r1);
    BUILD_MASK(z3, a3r0, a3r1);
    acc00 = MF8(a1r0, b00, acc00);
    acc00 = MF8(a2r0, b10, acc00);
    acc00 = MF8(a3r0, b20, acc00);
    acc01 = MF8(a1r0, b01, acc01);
    acc01 = MF8(a2r0, b11, acc01);
    acc01 = MF8(a3r0, b21, acc01);
    acc10 = MF8(a1r1, b00, acc10);
    acc10 = MF8(a2r1, b10, acc10);
    acc10 = MF8(a3r1, b20, acc10);
    acc11 = MF8(a1r1, b01, acc11);
    acc11 = MF8(a2r1, b11, acc11);
    acc11 = MF8(a3r1, b21, acc11);
    if (tl < 3) {
      b00 = n00; b01 = n01; b10 = n10; b11 = n11; b20 = n20; b21 = n21;
    }
  }
}

// ---------------------------------------------------------------------------
// agg1_kernel (fused full-K, layer 1): grid 256, 512 threads (8 waves).
// Block rg owns rows rg*32..+32, loops over all 8 c-chunks of the K=8192
// reduction: {dump packed tile, load wave's uint4 of mask words, issue adj
// loads for c+1, 48 MFMA for c, pack c+1 into the other LDS tile, barrier}.
// Wave w handles j-tiles tg=w (t = c*32 + w*4 .. +4).
// After the c-loop: 8-wave LDS reduce -> complete Z1 rows -> gb0+relu ->
// Z1 @ w_ch (3 channels, from LDS) -> fp8 Hfrag2 for t=rg. Eliminates
// h_kernel<1> and the Zpart round-trip.
// ---------------------------------------------------------------------------
__global__ __launch_bounds__(512, 2) void agg1_kernel(
    const int* __restrict__ adj, uint* __restrict__ packed_g,
    const u64* __restrict__ Hf1, u64* __restrict__ Hf2,
    const float* __restrict__ w1, const float* __restrict__ w2,
    const float* __restrict__ w3, const float* __restrict__ gb0) {
  __shared__ __align__(16) char smraw[65536];
  uint* pt0 = (uint*)smraw;
  uint* pt1 = (uint*)(smraw + 8192);
  float (*red)[4][64][4] = (float (*)[4][64][4])(smraw + 16384);  // 32 KB
  float* wl = (float*)(smraw + 49152);  // [3][32][32] = 12 KB
  float* Zs = (float*)smraw;            // [32][33] overlay (post c-loop)
  const int tid = threadIdx.x;
  const int rg = blockIdx.x;
  const int w = tid >> 6, lane = tid & 63;
  // stage layer-2 weights
  for (int i = tid; i < 3072; i += 512) {
    const int chw = i >> 10;
    const float* wsrc = (chw == 0) ? w1 : (chw == 1) ? w2 : w3;
    wl[i] = wsrc[i & 1023];
  }
  // pack geometry (tid2 covers 1024 j-columns, rhalf splits 32 rows)
  const int tid2 = tid & 255, rhalf = tid >> 8;
  const int byte_base = (tid2 >> 5) * 1024 + ((tid2 >> 1) & 3) * 256 +
                        ((tid2 >> 3) & 3) * 4 + (tid2 & 1);
  const int* abase =
      adj + (size_t)rg * 32 * NN + (size_t)rhalf * 16 * NN + tid2 * 4;
  // prologue: pack c=0 into pt0
  {
    int4 a[16];
#pragma unroll
    for (int rr = 0; rr < 16; ++rr)
      a[rr] = *(const int4*)(abase + (size_t)rr * NN);
    unsigned char* pb = (unsigned char*)pt0;
#pragma unroll
    for (int rr = 0; rr < 16; ++rr) {
      const int r = rhalf * 16 + rr;
      const uint b = (uint)(a[rr].x & 3) | ((uint)(a[rr].y & 3) << 2) |
                     ((uint)(a[rr].z & 3) << 4) | ((uint)(a[rr].w & 3) << 6);
      pb[byte_base + (r & 15) * 16 + (r >> 4) * 2] = (unsigned char)b;
    }
  }
  __syncthreads();
  floatx4 acc00 = {0.f, 0.f, 0.f, 0.f}, acc01 = {0.f, 0.f, 0.f, 0.f};
  floatx4 acc10 = {0.f, 0.f, 0.f, 0.f}, acc11 = {0.f, 0.f, 0.f, 0.f};
  for (int c = 0; c < 8; ++c) {
    uint* ptc = (c & 1) ? pt1 : pt0;
    uint* ptn = (c & 1) ? pt0 : pt1;
    int4 a[16];
    if (c < 7) {  // issue next chunk's adj loads before the MFMAs
#pragma unroll
      for (int rr = 0; rr < 16; ++rr)
        a[rr] = *(const int4*)(abase + (c + 1) * 1024 + (size_t)rr * NN);
    }
    // dump current packed tile for layer 2
    uint* pg = packed_g + ((size_t)rg * 8 + c) * 2048;
    *(uint4*)(pg + tid * 4) = *(const uint4*)(ptc + tid * 4);
    // wave's mask words (tg = w) and fragment base
    const uint4 mkv = *(const uint4*)(ptc + w * 256 + lane * 4);
    const u64* hp = Hf1 + (size_t)(c * 32 + w * 4) * 128 + lane;
    phaseB4(mkv, hp, acc00, acc01, acc10, acc11);
    if (c < 7) {
      unsigned char* pb = (unsigned char*)ptn;
#pragma unroll
      for (int rr = 0; rr < 16; ++rr) {
        const int r = rhalf * 16 + rr;
        const uint b = (uint)(a[rr].x & 3) | ((uint)(a[rr].y & 3) << 2) |
                       ((uint)(a[rr].z & 3) << 4) | ((uint)(a[rr].w & 3) << 6);
        pb[byte_base + (r & 15) * 16 + (r >> 4) * 2] = (unsigned char)b;
      }
    }
    __syncthreads();
  }
  // reduce across 8 waves
#pragma unroll
  for (int r = 0; r < 4; ++r) {
    red[w][0][lane][r] = acc00[r];
    red[w][1][lane][r] = acc01[r];
    red[w][2][lane][r] = acc10[r];
    red[w][3][lane][r] = acc11[r];
  }
  __syncthreads();
  if (w == 0) {
    const int m = lane & 15, q = lane >> 4;
#pragma unroll
    for (int r = 0; r < 4; ++r) {
      float c00 = 0.f, c01 = 0.f, c10 = 0.f, c11 = 0.f;
#pragma unroll
      for (int i = 0; i < 8; ++i) {
        c00 += red[i][0][lane][r];
        c01 += red[i][1][lane][r];
        c10 += red[i][2][lane][r];
        c11 += red[i][3][lane][r];
      }
      const int ro = q * 4 + r;
      float z00 = 0.5f * c00 + gb0[m];
      float z01 = 0.5f * c01 + gb0[16 + m];
      float z10 = 0.5f * c10 + gb0[m];
      float z11 = 0.5f * c11 + gb0[16 + m];
      z00 = z00 > 0.f ? z00 : 0.f;
      z01 = z01 > 0.f ? z01 : 0.f;
      z10 = z10 > 0.f ? z10 : 0.f;
      z11 = z11 > 0.f ? z11 : 0.f;
      Zs[ro * 33 + m] = z00;
      Zs[ro * 33 + 16 + m] = z01;
      Zs[(ro + 16) * 33 + m] = z10;
      Zs[(ro + 16) * 33 + 16 + m] = z11;
    }
  }
  __syncthreads();
  // epilogue: Hf2 = fp8(Z1 @ w_ch) fragments for t = rg
  if (tid < 384) {
    const int chp = tid >> 7, rem = tid & 127;
    const int tile = rem >> 6, l2 = rem & 63;
    const int n = tile * 16 + (l2 & 15), j0 = (l2 >> 4) * 8;
    const float* wc = wl + chp * 1024;
    float av[8];
#pragma unroll
    for (int e = 0; e < 8; ++e) {
      float acc = 0.f;
      const float* zr = Zs + (j0 + e) * 33;
#pragma unroll
      for (int d = 0; d < 32; ++d) acc += zr[d] * wc[d * 32 + n];
      av[e] = acc;
    }
    int lo = __builtin_amdgcn_cvt_pk_fp8_f32(av[0], av[1], 0, false);
    lo = __builtin_amdgcn_cvt_pk_fp8_f32(av[2], av[3], lo, true);
    int hi = __builtin_amdgcn_cvt_pk_fp8_f32(av[4], av[5], 0, false);
    hi = __builtin_amdgcn_cvt_pk_fp8_f32(av[6], av[7], hi, true);
    Hf2[(((size_t)chp * 256 + rg) * 2 + tile) * 64 + l2] =
        ((u64)(uint)hi << 32) | (uint)(uint)lo;
  }
}

// ---------------------------------------------------------------------------
// agg2_kernel (fused full-K, layer 2): grid 256, 512 threads. Mask words
// straight from the packed buffer (L2-resident). Complete Z2 rows in-block
// -> gb1+relu -> column-sum over 32 rows -> partials[rg][32]. Eliminates
// pool_kernel and the second Zpart round-trip.
// ---------------------------------------------------------------------------
__global__ __launch_bounds__(512, 2) void agg2_kernel(
    const uint* __restrict__ packed_g, const u64* __restrict__ Hf2,
    const float* __restrict__ gb1, float* __restrict__ partials) {
  __shared__ float red[8][4][64][4];
  const int tid = threadIdx.x;
  const int rg = blockIdx.x;
  const int w = tid >> 6, lane = tid & 63;
  floatx4 acc00 = {0.f, 0.f, 0.f, 0.f}, acc01 = {0.f, 0.f, 0.f, 0.f};
  floatx4 acc10 = {0.f, 0.f, 0.f, 0.f}, acc11 = {0.f, 0.f, 0.f, 0.f};
  const uint* pgb = packed_g + (size_t)rg * 8 * 2048 + w * 256 + lane * 4;
  for (int c = 0; c < 8; ++c) {
    const uint4 mkv = *(const uint4*)(pgb + c * 2048);
    const u64* hp = Hf2 + (size_t)(c * 32 + w * 4) * 128 + lane;
    phaseB4(mkv, hp, acc00, acc01, acc10, acc11);
  }
#pragma unroll
  for (int r = 0; r < 4; ++r) {
    red[w][0][lane][r] = acc00[r];
    red[w][1][lane][r] = acc01[r];
    red[w][2][lane][r] = acc10[r];
    red[w][3][lane][r] = acc11[r];
  }
  __syncthreads();
  if (w == 0) {
    const int m = lane & 15;
    float s0 = 0.f, s1 = 0.f;
#pragma unroll
    for (int r = 0; r < 4; ++r) {
      float c00 = 0.f, c01 = 0.f, c10 = 0.f, c11 = 0.f;
#pragma unroll
      for (int i = 0; i < 8; ++i) {
        c00 += red[i][0][lane][r];
        c01 += red[i][1][lane][r];
        c10 += red[i][2][lane][r];
        c11 += red[i][3][lane][r];
      }
      float z00 = 0.5f * c00 + gb1[m];
      float z01 = 0.5f * c01 + gb1[16 + m];
      float z10 = 0.5f * c10 + gb1[m];
      float z11 = 0.5f * c11 + gb1[16 + m];
      s0 += (z00 > 0.f ? z00 : 0.f) + (z10 > 0.f ? z10 : 0.f);
      s1 += (z01 > 0.f ? z01 : 0.f) + (z11 > 0.f ? z11 : 0.f);
    }
    s0 += __shfl_xor(s0, 16);
    s0 += __shfl_xor(s0, 32);
    s1 += __shfl_xor(s1, 16);
    s1 += __shfl_xor(s1, 32);
    if ((lane >> 4) == 0) {
      partials[rg * 32 + m] = s0;
      partials[rg * 32 + 16 + m] = s1;
    }
  }
}

// ---------------------------------------------------------------------------
// fc_kernel: reduce pooled partials (np x 32), fc0+relu, fc1, sigmoid
// ---------------------------------------------------------------------------
__global__ __launch_bounds__(256) void fc_kernel(
    const float* __restrict__ partials, int np, const float* __restrict__ W0,
    const float* __restrict__ b0, const float* __restrict__ W1,
    const float* __restrict__ b1, float* __restrict__ out) {
  __shared__ float acc8[8][32];
  __shared__ float z[32], y[32];
  const int tid = threadIdx.x;
  const int col = tid & 31, ch = tid >> 5;
  float s = 0.f;
  for (int i = ch; i < np; i += 8) s += partials[(size_t)i * 32 + col];
  acc8[ch][col] = s;
  __syncthreads();
  if (tid < 32) {
    float t = 0.f;
#pragma unroll
    for (int i = 0; i < 8; ++i) t += acc8[i][tid];
    z[tid] = t;
  }
  __syncthreads();
  if (tid < 32) {
    float acc = b0[tid];
    for (int n = 0; n < 32; ++n) acc += W0[tid * 32 + n] * z[n];
    y[tid] = acc > 0.f ? acc : 0.f;
  }
  __syncthreads();
  if (tid == 0) {
    float acc = b1[0];
    for (int mm = 0; mm < 32; ++mm) acc += W1[mm] * y[mm];
    out[0] = 1.f / (1.f + expf(-acc));
  }
}

extern "C" void kernel_launch(void* const* d_in, const int* in_sizes, int n_in,
                              void* d_out, int out_size, void* d_ws,
                              size_t ws_size, hipStream_t stream) {
  const float* V   = (const float*)d_in[0];
  const int*   adj = (const int*)d_in[1];
  const float *w10 = (const float*)d_in[2], *w20 = (const float*)d_in[3],
              *w30 = (const float*)d_in[4], *gb0 = (const float*)d_in[5];
  const float *w11 = (const float*)d_in[6], *w21 = (const float*)d_in[7],
              *w31 = (const float*)d_in[8], *gb1 = (const float*)d_in[9];
  const float *fW0 = (const float*)d_in[10], *fb0 = (const float*)d_in[11],
              *fW1 = (const float*)d_in[12], *fb1 = (const float*)d_in[13];
  float* out = (float*)d_out;
  char* ws = (char*)d_ws;

  u64*   Hf1      = (u64*)ws;                    //   786,432 B
  u64*   Hf2      = (u64*)(ws + 786432);         //   786,432 B
  uint*  packed   = (uint*)(ws + 1572864);       // 16,777,216 B
  float* partials = (float*)(ws + 18350080);     //    32,768 B

  h_kernel<<<dim3(128, 3), 256, 0, stream>>>(V, w10, w20, w30, Hf1);
  agg1_kernel<<<256, 512, 0, stream>>>(adj, packed, Hf1, Hf2, w11, w21, w31,
                                       gb0);
  agg2_kernel<<<256, 512, 0, stream>>>(packed, Hf2, gb1, partials);
  fc_kernel<<<1, 256, 0, stream>>>(partials, 256, fW0, fb0, fW1, fb1, out);
}